// Round 10
// baseline (874.397 us; speedup 1.0000x reference)
//
#include <hip/hip_runtime.h>
#include <math.h>

#define NTOK 8192
#define DMODEL 1024
#define DFF 4096
#define NEXP 8
#define TILE 256
#define MAXTILES 72
#define MAXROWS (MAXTILES * TILE)
#define MOE_EPS 1e-9f
#define REG 8192  // u16 per (dbuf,kk) region: 256 rows * 32 cols = 16 KB

typedef unsigned short u16;
typedef __bf16 bf16x8 __attribute__((ext_vector_type(8)));
typedef float f32x4 __attribute__((ext_vector_type(4)));

struct Ctrl {
    int counts[NEXP];
    int fill[NEXP];
    int padded_off[NEXP];
    int n_tiles;
    int tile_expert[MAXTILES];
    int tile_base[MAXTILES];
    int tile_valid[MAXTILES];
    float imp[NEXP];
    float zacc;
};

__device__ __forceinline__ u16 f2bf(float f) {
    unsigned u = __float_as_uint(f);
    unsigned r = u + 0x7fffu + ((u >> 16) & 1u);
    return (u16)(r >> 16);
}

__device__ __forceinline__ void load16(const void* g, void* l) {
    __builtin_amdgcn_global_load_lds((__attribute__((address_space(1))) void*)g,
                                     (__attribute__((address_space(3))) void*)l,
                                     16, 0, 0);
}

__device__ __forceinline__ float gelu_fast(float h) {
    float u = h * (1.5957691216f + 0.0713548162f * h * h);
    return h / (1.f + __expf(-u));
}

// ---------------- fp32 -> bf16 convert (w1, w2) ----------------
__global__ __launch_bounds__(256) void k_convert(const float* __restrict__ src,
                                                 u16* __restrict__ dst, int n4) {
    int i = blockIdx.x * 256 + threadIdx.x;
    int stride = gridDim.x * 256;
    for (; i < n4; i += stride) {
        float4 v = ((const float4*)src)[i];
        ushort4 o;
        o.x = f2bf(v.x); o.y = f2bf(v.y); o.z = f2bf(v.z); o.w = f2bf(v.w);
        ((ushort4*)dst)[i] = o;
    }
}

// ---------------- router (+ fused x->bf16 conversion) ----------------
__global__ __launch_bounds__(256) void k_router(const float* __restrict__ x,
                                                const float* __restrict__ rw,
                                                u16* __restrict__ xb,
                                                int* __restrict__ top_idx,
                                                float* __restrict__ top_w,
                                                Ctrl* __restrict__ ctrl) {
    __shared__ float srw[NEXP * DMODEL];
    __shared__ float simp[NEXP];
    __shared__ float szl;
    int tid = threadIdx.x;
    for (int i = tid; i < NEXP * DMODEL / 4; i += 256)
        ((float4*)srw)[i] = ((const float4*)rw)[i];
    if (tid < NEXP) simp[tid] = 0.f;
    if (tid == 0) szl = 0.f;
    __syncthreads();

    int lane = tid & 63;
    int n = blockIdx.x * 4 + (tid >> 6);
    float p[NEXP];
#pragma unroll
    for (int e = 0; e < NEXP; ++e) p[e] = 0.f;
    const float4* xr = (const float4*)(x + (size_t)n * DMODEL);
    u16 xs[16];
#pragma unroll
    for (int j = 0; j < 4; ++j) {
        float4 xv = xr[lane * 4 + j];
        int d = (lane * 4 + j) * 4;
        xs[j * 4 + 0] = f2bf(xv.x);
        xs[j * 4 + 1] = f2bf(xv.y);
        xs[j * 4 + 2] = f2bf(xv.z);
        xs[j * 4 + 3] = f2bf(xv.w);
#pragma unroll
        for (int e = 0; e < NEXP; ++e) {
            const float* r = srw + e * DMODEL + d;
            p[e] += xv.x * r[0] + xv.y * r[1] + xv.z * r[2] + xv.w * r[3];
        }
    }
    {
        uint4* dst = (uint4*)(xb + (size_t)n * DMODEL + lane * 16);
        dst[0] = ((const uint4*)xs)[0];
        dst[1] = ((const uint4*)xs)[1];
    }
#pragma unroll
    for (int e = 0; e < NEXP; ++e) {
#pragma unroll
        for (int off = 32; off > 0; off >>= 1) p[e] += __shfl_xor(p[e], off);
    }
    if (lane == 0) {
        float m = p[0];
#pragma unroll
        for (int e = 1; e < NEXP; ++e) m = fmaxf(m, p[e]);
        float pr[NEXP];
        float s = 0.f;
#pragma unroll
        for (int e = 0; e < NEXP; ++e) { pr[e] = expf(p[e] - m); s += pr[e]; }
        float inv = 1.f / s;
#pragma unroll
        for (int e = 0; e < NEXP; ++e) pr[e] *= inv;
        float lse = m + logf(s);
        int i0 = 0; float v0 = pr[0];
#pragma unroll
        for (int e = 1; e < NEXP; ++e) if (pr[e] > v0) { v0 = pr[e]; i0 = e; }
        int i1 = -1; float v1 = -1.f;
#pragma unroll
        for (int e = 0; e < NEXP; ++e) if (e != i0 && pr[e] > v1) { v1 = pr[e]; i1 = e; }
        float den = v0 + v1 + MOE_EPS;
        top_idx[n * 2] = i0;
        top_idx[n * 2 + 1] = i1;
        top_w[n * 2] = v0 / den;
        top_w[n * 2 + 1] = v1 / den;
#pragma unroll
        for (int e = 0; e < NEXP; ++e) atomicAdd(&simp[e], pr[e]);
        atomicAdd(&szl, lse * lse);
    }
    __syncthreads();
    if (tid < NEXP) atomicAdd(&ctrl->imp[tid], simp[tid]);
    if (tid == 255) atomicAdd(&ctrl->zacc, szl);
}

// ---------------- build schedule (256-row tiles) ----------------
__global__ __launch_bounds__(256) void k_build(const int* __restrict__ top_idx,
                                               Ctrl* __restrict__ ctrl,
                                               int* __restrict__ tok_idx,
                                               float* __restrict__ tok_w) {
    __shared__ int cnt[NEXP];
    __shared__ int off[NEXP];
    __shared__ int tiles[NEXP];
    int tid = threadIdx.x;
    if (tid < NEXP) cnt[tid] = 0;
    __syncthreads();
    for (int i = tid; i < NTOK * 2; i += 256) atomicAdd(&cnt[top_idx[i]], 1);
    __syncthreads();
    if (tid == 0) {
        int o = 0, t = 0;
        for (int e = 0; e < NEXP; ++e) {
            int c = cnt[e];
            int te = (c + TILE - 1) / TILE;
            ctrl->counts[e] = c;
            ctrl->padded_off[e] = o;
            off[e] = o;
            tiles[e] = te;
            for (int i = 0; i < te; ++i) {
                ctrl->tile_expert[t] = e;
                ctrl->tile_base[t] = o + i * TILE;
                int v = c - i * TILE;
                ctrl->tile_valid[t] = v > TILE ? TILE : v;
                ++t;
            }
            o += te * TILE;
        }
        ctrl->n_tiles = t;
    }
    __syncthreads();
    for (int e = 0; e < NEXP; ++e) {
        int start = off[e] + cnt[e];
        int end = off[e] + tiles[e] * TILE;
        for (int i = start + tid; i < end; i += 256) {
            tok_idx[i] = 0;
            tok_w[i] = 0.f;
        }
    }
}

// ---------------- fill token lists ----------------
__global__ __launch_bounds__(256) void k_fill(const int* __restrict__ top_idx,
                                              const float* __restrict__ top_w,
                                              Ctrl* __restrict__ ctrl,
                                              int* __restrict__ tok_idx,
                                              float* __restrict__ tok_w) {
    int n = blockIdx.x * 256 + threadIdx.x;
    if (n >= NTOK) return;
#pragma unroll
    for (int k = 0; k < 2; ++k) {
        int e = top_idx[n * 2 + k];
        int pos = atomicAdd(&ctrl->fill[e], 1);
        int slot = ctrl->padded_off[e] + pos;
        tok_idx[slot] = n;
        tok_w[slot] = top_w[n * 2 + k];
    }
}

// ======== 256x256 4-phase/K-tile, unit-granular staging, counted vmcnt(6) ========
// LDS: sA/sB[2 dbuf][2 kk][256 rows][32 cols] u16; unit = one (matrix,dbuf,kk)
// region = 16 KB = 2 gloads/thread (512 thr).  Waves: 8 = 2M x 4N, tile 128x64.
// Read schedule per K-tile kt (buf p): ph0 A0(m0-3)+B0 -> 16 MFMA; ph1 A0(m4-7)
// (B kept in regs) -> 16; ph2 A1(m0-3)+B1 -> 16; ph3 A1(m4-7) -> 16.
// Stage-into-region-freed-by-previous-phase: ph0 -> A(p^1,kt+1,kk1); ph1 ->
// B(p,kt+2,kk0); ph2 -> A(p,kt+2,kk0); ph3 -> B(p,kt+2,kk1).  Every unit lands
// >=5 stages before its reader's vmcnt(6) (ledger checked incl. prologue/tail).
// Swizzle (r8-proven, 0 conflicts): stage chunk lc=(f&3)^((row>>1)&3); read
// csw=(lg^((l15>>1)&3))*8.
#define KLOOP8(SA, SB, NK)                                                            \
    SA(0, 0, 0); SB(0, 0, 0); SA(0, 0, 1); SB(0, 0, 1);                               \
    SB(1, 1, 0); SA(1, 1, 0); SB(1, 1, 1);                                            \
    for (int kt = 0; kt < (NK); ++kt) {                                               \
        int p = kt & 1;                                                               \
        const u16* A0 = sA + (p * 2 + 0) * REG;                                       \
        const u16* A1 = sA + (p * 2 + 1) * REG;                                       \
        const u16* B0 = sB + (p * 2 + 0) * REG;                                       \
        const u16* B1 = sB + (p * 2 + 1) * REG;                                       \
        bf16x8 a[4], b[4];                                                            \
        int last = (kt == (NK) - 1);                                                  \
        /* ---- ph0 ---- */                                                           \
        if (last) asm volatile("s_waitcnt vmcnt(0)" ::: "memory");                    \
        else      asm volatile("s_waitcnt vmcnt(6)" ::: "memory");                    \
        __builtin_amdgcn_s_barrier();                                                 \
        _Pragma("unroll") for (int m = 0; m < 4; ++m) a[m] = *(const bf16x8*)(A0 + aoff[m]); \
        _Pragma("unroll") for (int n = 0; n < 4; ++n) b[n] = *(const bf16x8*)(B0 + boff[n]); \
        if (kt + 1 < (NK)) { SA(p ^ 1, kt + 1, 1); }                                  \
        asm volatile("s_waitcnt lgkmcnt(0)" ::: "memory");                            \
        __builtin_amdgcn_sched_barrier(0);                                            \
        __builtin_amdgcn_s_setprio(1);                                                \
        _Pragma("unroll") for (int m = 0; m < 4; ++m)                                 \
            _Pragma("unroll") for (int n = 0; n < 4; ++n)                             \
                acc[m][n] = __builtin_amdgcn_mfma_f32_16x16x32_bf16(a[m], b[n], acc[m][n], 0, 0, 0); \
        __builtin_amdgcn_s_setprio(0);                                                \
        __builtin_amdgcn_sched_barrier(0);                                            \
        /* ---- ph1 ---- */                                                           \
        if (last) asm volatile("s_waitcnt vmcnt(0)" ::: "memory");                    \
        else      asm volatile("s_waitcnt vmcnt(6)" ::: "memory");                    \
        __builtin_amdgcn_s_barrier();                                                 \
        _Pragma("unroll") for (int m = 0; m < 4; ++m) a[m] = *(const bf16x8*)(A0 + aoff[m + 4]); \
        if (kt + 2 < (NK)) { SB(p, kt + 2, 0); }                                      \
        asm volatile("s_waitcnt lgkmcnt(0)" ::: "memory");                            \
        __builtin_amdgcn_sched_barrier(0);                                            \
        __builtin_amdgcn_s_setprio(1);                                                \
        _Pragma("unroll") for (int m = 0; m < 4; ++m)                                 \
            _Pragma("unroll") for (int n = 0; n < 4; ++n)                             \
                acc[m + 4][n] = __builtin_amdgcn_mfma_f32_16x16x32_bf16(a[m], b[n], acc[m + 4][n], 0, 0, 0); \
        __builtin_amdgcn_s_setprio(0);                                                \
        __builtin_amdgcn_sched_barrier(0);                                            \
        /* ---- ph2 ---- */                                                           \
        if (last) asm volatile("s_waitcnt vmcnt(0)" ::: "memory");                    \
        else      asm volatile("s_waitcnt vmcnt(6)" ::: "memory");                    \
        __builtin_amdgcn_s_barrier();                                                 \
        _Pragma("unroll") for (int m = 0; m < 4; ++m) a[m] = *(const bf16x8*)(A1 + aoff[m]); \
        _Pragma("unroll") for (int n = 0; n < 4; ++n) b[n] = *(const bf16x8*)(B1 + boff[n]); \
        if (kt + 2 < (NK)) { SA(p, kt + 2, 0); }                                      \
        asm volatile("s_waitcnt lgkmcnt(0)" ::: "memory");                            \
        __builtin_amdgcn_sched_barrier(0);                                            \
        __builtin_amdgcn_s_setprio(1);                                                \
        _Pragma("unroll") for (int m = 0; m < 4; ++m)                                 \
            _Pragma("unroll") for (int n = 0; n < 4; ++n)                             \
                acc[m][n] = __builtin_amdgcn_mfma_f32_16x16x32_bf16(a[m], b[n], acc[m][n], 0, 0, 0); \
        __builtin_amdgcn_s_setprio(0);                                                \
        __builtin_amdgcn_sched_barrier(0);                                            \
        /* ---- ph3 ---- */                                                           \
        if (last) asm volatile("s_waitcnt vmcnt(0)" ::: "memory");                    \
        else      asm volatile("s_waitcnt vmcnt(6)" ::: "memory");                    \
        __builtin_amdgcn_s_barrier();                                                 \
        _Pragma("unroll") for (int m = 0; m < 4; ++m) a[m] = *(const bf16x8*)(A1 + aoff[m + 4]); \
        if (kt + 2 < (NK)) { SB(p, kt + 2, 1); }                                      \
        asm volatile("s_waitcnt lgkmcnt(0)" ::: "memory");                            \
        __builtin_amdgcn_sched_barrier(0);                                            \
        __builtin_amdgcn_s_setprio(1);                                                \
        _Pragma("unroll") for (int m = 0; m < 4; ++m)                                 \
            _Pragma("unroll") for (int n = 0; n < 4; ++n)                             \
                acc[m + 4][n] = __builtin_amdgcn_mfma_f32_16x16x32_bf16(a[m], b[n], acc[m + 4][n], 0, 0, 0); \
        __builtin_amdgcn_s_setprio(0);                                                \
        __builtin_amdgcn_sched_barrier(0);                                            \
    }

// ============ GEMM1: H = gelu(Xg @ w1^T + b1) [256x256, 8 waves] ============
// grid 1152 1-D; XCD remap: t=(flat&7)+8*(flat>>7), n0f=(flat>>3)&15.
__global__ __launch_bounds__(512, 1) void k_gemm1(const u16* __restrict__ xb,
                                                  const u16* __restrict__ w1b,
                                                  const float* __restrict__ b1,
                                                  const int* __restrict__ tok_idx,
                                                  const Ctrl* __restrict__ ctrl,
                                                  u16* __restrict__ H) {
    int flat = blockIdx.x;
    int t = (flat & 7) + ((flat >> 7) << 3);
    int n0 = ((flat >> 3) & 15) * TILE;
    if (t >= ctrl->n_tiles) return;
    int e = ctrl->tile_expert[t];
    int rbase = ctrl->tile_base[t];

    __shared__ __align__(16) u16 sA[2 * 2 * REG];
    __shared__ __align__(16) u16 sB[2 * 2 * REG];

    int tid = threadIdx.x;
    const u16* aS[2];
    const u16* bS[2];
    int fo[2];
#pragma unroll
    for (int q = 0; q < 2; ++q) {
        int f = q * 512 + tid;                 // 0..1023
        int row = f >> 2;                      // 0..255
        int lc = (f & 3) ^ ((row >> 1) & 3);   // inverse-swizzled source chunk
        aS[q] = xb + (size_t)tok_idx[rbase + row] * DMODEL + lc * 8;
        bS[q] = w1b + (size_t)e * DFF * DMODEL + (size_t)(n0 + row) * DMODEL + lc * 8;
        fo[q] = f * 8;
    }

#define SA1(pp, kt, kk)                                                               \
    do { _Pragma("unroll") for (int q = 0; q < 2; ++q)                                \
        load16(aS[q] + (kt) * 64 + (kk) * 32, &sA[((pp) * 2 + (kk)) * REG + fo[q]]); } while (0)
#define SB1(pp, kt, kk)                                                               \
    do { _Pragma("unroll") for (int q = 0; q < 2; ++q)                                \
        load16(bS[q] + (kt) * 64 + (kk) * 32, &sB[((pp) * 2 + (kk)) * REG + fo[q]]); } while (0)

    int lane = tid & 63, w = tid >> 6;
    int wr = w >> 2, wc = w & 3;               // 2M x 4N; wave tile 128x64
    int l15 = lane & 15, lg = lane >> 4;
    int csw = (lg ^ ((l15 >> 1) & 3)) * 8;

    int aoff[8], boff[4];
#pragma unroll
    for (int m = 0; m < 8; ++m) aoff[m] = (wr * 128 + m * 16 + l15) * 32 + csw;
#pragma unroll
    for (int n = 0; n < 4; ++n) boff[n] = (wc * 64 + n * 16 + l15) * 32 + csw;

    f32x4 acc[8][4];
#pragma unroll
    for (int m = 0; m < 8; ++m)
#pragma unroll
        for (int n = 0; n < 4; ++n) acc[m][n] = (f32x4){0.f, 0.f, 0.f, 0.f};

    KLOOP8(SA1, SB1, DMODEL / 64)
#undef SA1
#undef SB1

    float bias[4];
#pragma unroll
    for (int n = 0; n < 4; ++n) bias[n] = b1[e * DFF + n0 + wc * 64 + n * 16 + l15];
#pragma unroll
    for (int m = 0; m < 8; ++m)
#pragma unroll
        for (int n = 0; n < 4; ++n) {
            int gcol = n0 + wc * 64 + n * 16 + l15;
#pragma unroll
            for (int r = 0; r < 4; ++r) {
                int grow = wr * 128 + m * 16 + lg * 4 + r;
                float h = acc[m][n][r] + bias[n];
                H[(size_t)(rbase + grow) * DFF + gcol] = f2bf(gelu_fast(h));
            }
        }
}

// ============ GEMM2: y += w*(H @ w2^T + b2) [256x256, split-K x2, 8 waves] ============
// grid 576 1-D; t=(flat&7)+8*(flat>>6); n0f=(flat>>3)&3; chunk=(flat>>5)&1.
__global__ __launch_bounds__(512, 1) void k_gemm2(const u16* __restrict__ H,
                                                  const u16* __restrict__ w2b,
                                                  const float* __restrict__ b2,
                                                  const int* __restrict__ tok_idx,
                                                  const float* __restrict__ tok_w,
                                                  const Ctrl* __restrict__ ctrl,
                                                  float* __restrict__ y) {
    int flat = blockIdx.x;
    int t = (flat & 7) + ((flat >> 6) << 3);
    int n0 = ((flat >> 3) & 3) * TILE;
    int chunk = (flat >> 5) & 1;
    if (t >= ctrl->n_tiles) return;
    int e = ctrl->tile_expert[t];
    int rbase = ctrl->tile_base[t];
    int valid = ctrl->tile_valid[t];
    int kbase = chunk * (DFF / 2);

    __shared__ __align__(16) u16 sA[2 * 2 * REG];
    __shared__ __align__(16) u16 sB[2 * 2 * REG];

    int tid = threadIdx.x;
    const u16* aS[2];
    const u16* bS[2];
    int fo[2];
#pragma unroll
    for (int q = 0; q < 2; ++q) {
        int f = q * 512 + tid;
        int row = f >> 2;
        int lc = (f & 3) ^ ((row >> 1) & 3);
        aS[q] = H + (size_t)(rbase + row) * DFF + kbase + lc * 8;
        bS[q] = w2b + (size_t)e * DMODEL * DFF + (size_t)(n0 + row) * DFF + kbase + lc * 8;
        fo[q] = f * 8;
    }

#define SA2(pp, kt, kk)                                                               \
    do { _Pragma("unroll") for (int q = 0; q < 2; ++q)                                \
        load16(aS[q] + (kt) * 64 + (kk) * 32, &sA[((pp) * 2 + (kk)) * REG + fo[q]]); } while (0)
#define SB2(pp, kt, kk)                                                               \
    do { _Pragma("unroll") for (int q = 0; q < 2; ++q)                                \
        load16(bS[q] + (kt) * 64 + (kk) * 32, &sB[((pp) * 2 + (kk)) * REG + fo[q]]); } while (0)

    int lane = tid & 63, w = tid >> 6;
    int wr = w >> 2, wc = w & 3;
    int l15 = lane & 15, lg = lane >> 4;
    int csw = (lg ^ ((l15 >> 1) & 3)) * 8;

    int aoff[8], boff[4];
#pragma unroll
    for (int m = 0; m < 8; ++m) aoff[m] = (wr * 128 + m * 16 + l15) * 32 + csw;
#pragma unroll
    for (int n = 0; n < 4; ++n) boff[n] = (wc * 64 + n * 16 + l15) * 32 + csw;

    f32x4 acc[8][4];
#pragma unroll
    for (int m = 0; m < 8; ++m)
#pragma unroll
        for (int n = 0; n < 4; ++n) acc[m][n] = (f32x4){0.f, 0.f, 0.f, 0.f};

    KLOOP8(SA2, SB2, DFF / 64 / 2)
#undef SA2
#undef SB2

    float bias[4];
#pragma unroll
    for (int n = 0; n < 4; ++n)
        bias[n] = (chunk == 0) ? b2[e * DMODEL + n0 + wc * 64 + n * 16 + l15] : 0.f;
#pragma unroll
    for (int m = 0; m < 8; ++m)
#pragma unroll
        for (int n = 0; n < 4; ++n) {
            int gcol = n0 + wc * 64 + n * 16 + l15;
#pragma unroll
            for (int r = 0; r < 4; ++r) {
                int grow = wr * 128 + m * 16 + lg * 4 + r;
                if (grow < valid) {
                    int slot = rbase + grow;
                    int tok = tok_idx[slot];
                    float wgt = tok_w[slot];
                    unsafeAtomicAdd(&y[(size_t)tok * DMODEL + gcol],
                                    wgt * (acc[m][n][r] + bias[n]));
                }
            }
        }
}

// ---------------- finalize ----------------
__global__ void k_final(const Ctrl* __restrict__ ctrl, float* __restrict__ out) {
    if (blockIdx.x == 0 && threadIdx.x == 0) {
        float imp[NEXP], ld[NEXP];
        float imps = 0.f, loads = 0.f;
        for (int e = 0; e < NEXP; ++e) {
            imp[e] = ctrl->imp[e];
            ld[e] = (float)ctrl->counts[e];
            imps += imp[e];
            loads += ld[e];
        }
        float bal = 0.f;
        for (int e = 0; e < NEXP; ++e)
            bal += (imp[e] / (imps + MOE_EPS)) * (ld[e] / (loads + MOE_EPS));
        bal *= (float)NEXP;
        float z = ctrl->zacc / (float)NTOK;
        float aux = 0.01f * bal + 0.001f * z;
        size_t base = (size_t)NTOK * DMODEL;
        out[base] = aux;
        for (int e = 0; e < NEXP; ++e) out[base + 1 + e] = ld[e];
        for (int e = 0; e < NEXP; ++e) out[base + 9 + e] = imp[e];
    }
}

extern "C" void kernel_launch(void* const* d_in, const int* in_sizes, int n_in,
                              void* d_out, int out_size, void* d_ws, size_t ws_size,
                              hipStream_t stream) {
    (void)in_sizes; (void)n_in; (void)out_size; (void)ws_size;
    const float* x  = (const float*)d_in[0];
    const float* rw = (const float*)d_in[1];
    const float* w1 = (const float*)d_in[2];
    const float* b1 = (const float*)d_in[3];
    const float* w2 = (const float*)d_in[4];
    const float* b2 = (const float*)d_in[5];
    float* out = (float*)d_out;

    char* p = (char*)d_ws;
    Ctrl* ctrl = (Ctrl*)p;          p += 4096;
    u16* xb    = (u16*)p;           p += (size_t)NTOK * DMODEL * 2;
    u16* w1b   = (u16*)p;           p += (size_t)NEXP * DFF * DMODEL * 2;
    u16* w2b   = (u16*)p;           p += (size_t)NEXP * DMODEL * DFF * 2;
    u16* Hbuf  = (u16*)p;           p += (size_t)MAXROWS * DFF * 2;
    int* tok_idx = (int*)p;         p += (size_t)MAXROWS * 4;
    float* tok_w = (float*)p;       p += (size_t)MAXROWS * 4;
    int* tIdx  = (int*)p;           p += (size_t)NTOK * 2 * 4;
    float* tW  = (float*)p;         p += (size_t)NTOK * 2 * 4;

    hipMemsetAsync(ctrl, 0, sizeof(Ctrl), stream);
    hipMemsetAsync(d_out, 0, (size_t)NTOK * DMODEL * sizeof(float), stream);

    k_convert<<<2048, 256, 0, stream>>>(w1, w1b, NEXP * DFF * DMODEL / 4);
    k_convert<<<2048, 256, 0, stream>>>(w2, w2b, NEXP * DMODEL * DFF / 4);

    k_router<<<NTOK / 4, 256, 0, stream>>>(x, rw, xb, tIdx, tW, ctrl);
    k_build<<<1, 256, 0, stream>>>(tIdx, ctrl, tok_idx, tok_w);
    k_fill<<<NTOK / 256, 256, 0, stream>>>(tIdx, tW, ctrl, tok_idx, tok_w);

    k_gemm1<<<MAXTILES * (DFF / TILE), 512, 0, stream>>>(xb, w1b, b1, tok_idx, ctrl, Hbuf);
    k_gemm2<<<MAXTILES * (DMODEL / TILE) * 2, 512, 0, stream>>>(Hbuf, w2b, b2, tok_idx, tok_w, ctrl, out);

    k_final<<<1, 64, 0, stream>>>(ctrl, out);
}

// Round 11
// 806.515 us; speedup vs baseline: 1.0842x; 1.0842x over previous
//
#include <hip/hip_runtime.h>
#include <math.h>

#define NTOK 8192
#define DMODEL 1024
#define DFF 4096
#define NEXP 8
#define TILE 128
#define MAXTILES 136
#define MAXROWS (MAXTILES * TILE)
#define MOE_EPS 1e-9f
#define REG 4096  // u16 per (dbuf,kk) region: 128 rows * 32 cols

typedef unsigned short u16;
typedef __bf16 bf16x8 __attribute__((ext_vector_type(8)));
typedef float f32x4 __attribute__((ext_vector_type(4)));

struct Ctrl {
    int counts[NEXP];
    int fill[NEXP];
    int padded_off[NEXP];
    int n_tiles;
    int tile_expert[MAXTILES];
    int tile_base[MAXTILES];
    int tile_valid[MAXTILES];
    float imp[NEXP];
    float zacc;
};

__device__ __forceinline__ u16 f2bf(float f) {
    unsigned u = __float_as_uint(f);
    unsigned r = u + 0x7fffu + ((u >> 16) & 1u);
    return (u16)(r >> 16);
}

__device__ __forceinline__ void load16(const void* g, void* l) {
    __builtin_amdgcn_global_load_lds((__attribute__((address_space(1))) void*)g,
                                     (__attribute__((address_space(3))) void*)l,
                                     16, 0, 0);
}

// fast GELU: h*sigmoid(1.59577h+0.071355h^3) (tanh-form), |err| < 1e-3
__device__ __forceinline__ float gelu_fast(float h) {
    float u = h * (1.5957691216f + 0.0713548162f * h * h);
    return h / (1.f + __expf(-u));
}

// ---------------- fp32 -> bf16 convert (w1, w2) ----------------
__global__ __launch_bounds__(256) void k_convert(const float* __restrict__ src,
                                                 u16* __restrict__ dst, int n4) {
    int i = blockIdx.x * 256 + threadIdx.x;
    int stride = gridDim.x * 256;
    for (; i < n4; i += stride) {
        float4 v = ((const float4*)src)[i];
        ushort4 o;
        o.x = f2bf(v.x); o.y = f2bf(v.y); o.z = f2bf(v.z); o.w = f2bf(v.w);
        ((ushort4*)dst)[i] = o;
    }
}

// ---------------- router (+ fused x->bf16 conversion) ----------------
__global__ __launch_bounds__(256) void k_router(const float* __restrict__ x,
                                                const float* __restrict__ rw,
                                                u16* __restrict__ xb,
                                                int* __restrict__ top_idx,
                                                float* __restrict__ top_w,
                                                Ctrl* __restrict__ ctrl) {
    __shared__ float srw[NEXP * DMODEL];
    __shared__ float simp[NEXP];
    __shared__ float szl;
    int tid = threadIdx.x;
    for (int i = tid; i < NEXP * DMODEL / 4; i += 256)
        ((float4*)srw)[i] = ((const float4*)rw)[i];
    if (tid < NEXP) simp[tid] = 0.f;
    if (tid == 0) szl = 0.f;
    __syncthreads();

    int lane = tid & 63;
    int n = blockIdx.x * 4 + (tid >> 6);
    float p[NEXP];
#pragma unroll
    for (int e = 0; e < NEXP; ++e) p[e] = 0.f;
    const float4* xr = (const float4*)(x + (size_t)n * DMODEL);
    u16 xs[16];
#pragma unroll
    for (int j = 0; j < 4; ++j) {
        float4 xv = xr[lane * 4 + j];
        int d = (lane * 4 + j) * 4;
        xs[j * 4 + 0] = f2bf(xv.x);
        xs[j * 4 + 1] = f2bf(xv.y);
        xs[j * 4 + 2] = f2bf(xv.z);
        xs[j * 4 + 3] = f2bf(xv.w);
#pragma unroll
        for (int e = 0; e < NEXP; ++e) {
            const float* r = srw + e * DMODEL + d;
            p[e] += xv.x * r[0] + xv.y * r[1] + xv.z * r[2] + xv.w * r[3];
        }
    }
    {
        uint4* dst = (uint4*)(xb + (size_t)n * DMODEL + lane * 16);
        dst[0] = ((const uint4*)xs)[0];
        dst[1] = ((const uint4*)xs)[1];
    }
#pragma unroll
    for (int e = 0; e < NEXP; ++e) {
#pragma unroll
        for (int off = 32; off > 0; off >>= 1) p[e] += __shfl_xor(p[e], off);
    }
    if (lane == 0) {
        float m = p[0];
#pragma unroll
        for (int e = 1; e < NEXP; ++e) m = fmaxf(m, p[e]);
        float pr[NEXP];
        float s = 0.f;
#pragma unroll
        for (int e = 0; e < NEXP; ++e) { pr[e] = expf(p[e] - m); s += pr[e]; }
        float inv = 1.f / s;
#pragma unroll
        for (int e = 0; e < NEXP; ++e) pr[e] *= inv;
        float lse = m + logf(s);
        int i0 = 0; float v0 = pr[0];
#pragma unroll
        for (int e = 1; e < NEXP; ++e) if (pr[e] > v0) { v0 = pr[e]; i0 = e; }
        int i1 = -1; float v1 = -1.f;
#pragma unroll
        for (int e = 0; e < NEXP; ++e) if (e != i0 && pr[e] > v1) { v1 = pr[e]; i1 = e; }
        float den = v0 + v1 + MOE_EPS;
        top_idx[n * 2] = i0;
        top_idx[n * 2 + 1] = i1;
        top_w[n * 2] = v0 / den;
        top_w[n * 2 + 1] = v1 / den;
#pragma unroll
        for (int e = 0; e < NEXP; ++e) atomicAdd(&simp[e], pr[e]);
        atomicAdd(&szl, lse * lse);
    }
    __syncthreads();
    if (tid < NEXP) atomicAdd(&ctrl->imp[tid], simp[tid]);
    if (tid == 255) atomicAdd(&ctrl->zacc, szl);
}

// ---------------- build schedule (128-row tiles) ----------------
__global__ __launch_bounds__(256) void k_build(const int* __restrict__ top_idx,
                                               Ctrl* __restrict__ ctrl,
                                               int* __restrict__ tok_idx,
                                               float* __restrict__ tok_w) {
    __shared__ int cnt[NEXP];
    __shared__ int off[NEXP];
    __shared__ int tiles[NEXP];
    int tid = threadIdx.x;
    if (tid < NEXP) cnt[tid] = 0;
    __syncthreads();
    for (int i = tid; i < NTOK * 2; i += 256) atomicAdd(&cnt[top_idx[i]], 1);
    __syncthreads();
    if (tid == 0) {
        int o = 0, t = 0;
        for (int e = 0; e < NEXP; ++e) {
            int c = cnt[e];
            int te = (c + TILE - 1) / TILE;
            ctrl->counts[e] = c;
            ctrl->padded_off[e] = o;
            off[e] = o;
            tiles[e] = te;
            for (int i = 0; i < te; ++i) {
                ctrl->tile_expert[t] = e;
                ctrl->tile_base[t] = o + i * TILE;
                int v = c - i * TILE;
                ctrl->tile_valid[t] = v > TILE ? TILE : v;
                ++t;
            }
            o += te * TILE;
        }
        ctrl->n_tiles = t;
    }
    __syncthreads();
    for (int e = 0; e < NEXP; ++e) {
        int start = off[e] + cnt[e];
        int end = off[e] + tiles[e] * TILE;
        for (int i = start + tid; i < end; i += 256) {
            tok_idx[i] = 0;
            tok_w[i] = 0.f;
        }
    }
}

// ---------------- fill token lists ----------------
__global__ __launch_bounds__(256) void k_fill(const int* __restrict__ top_idx,
                                              const float* __restrict__ top_w,
                                              Ctrl* __restrict__ ctrl,
                                              int* __restrict__ tok_idx,
                                              float* __restrict__ tok_w) {
    int n = blockIdx.x * 256 + threadIdx.x;
    if (n >= NTOK) return;
#pragma unroll
    for (int k = 0; k < 2; ++k) {
        int e = top_idx[n * 2 + k];
        int pos = atomicAdd(&ctrl->fill[e], 1);
        int slot = ctrl->padded_off[e] + pos;
        tok_idx[slot] = n;
        tok_w[slot] = top_w[n * 2 + k];
    }
}

// ======== 128x128 2-phase/K-tile counted-vmcnt K-loop ========
// vs r9: the per-phase `lgkmcnt(0)+sched_barrier(0)` pinning is REMOVED.
// ds_reads are plain C++ loads; compiler emits fine-grained lgkmcnt so reads
// interleave with MFMAs (the m97 pattern). vmcnt asms keep "memory" clobber:
// no C++ memory op (ds_read or gload_lds) crosses them, so the publish/free
// ordering and the vmcnt issue-count ledger still hold.
#define KLOOP2(STA, STB, NK)                                                          \
    STA(0, 0, 0); STB(0, 0, 0);                                                       \
    STA(0, 0, 1); STB(0, 0, 1);                                                       \
    STA(1, 1, 0); STB(1, 1, 0);                                                       \
    asm volatile("s_waitcnt vmcnt(8)" ::: "memory");                                  \
    __builtin_amdgcn_s_barrier();                                                     \
    for (int kt = 0; kt < (NK); ++kt) {                                               \
        int p = kt & 1;                                                               \
        const u16* Ar; const u16* Br;                                                 \
        bf16x8 a[4], b[4];                                                            \
        /* ---- ph0: kk0 ---- */                                                      \
        Ar = sA + (p * 2 + 0) * REG; Br = sB + (p * 2 + 0) * REG;                     \
        _Pragma("unroll") for (int m = 0; m < 4; ++m) a[m] = *(const bf16x8*)(Ar + aoff[m]); \
        _Pragma("unroll") for (int n = 0; n < 4; ++n) b[n] = *(const bf16x8*)(Br + boff[n]); \
        if (kt + 1 < (NK)) { STA(p ^ 1, kt + 1, 1); STB(p ^ 1, kt + 1, 1); }          \
        __builtin_amdgcn_s_setprio(1);                                                \
        _Pragma("unroll") for (int m = 0; m < 4; ++m)                                 \
            _Pragma("unroll") for (int n = 0; n < 4; ++n)                             \
                acc[m][n] = __builtin_amdgcn_mfma_f32_16x16x32_bf16(a[m], b[n], acc[m][n], 0, 0, 0); \
        __builtin_amdgcn_s_setprio(0);                                                \
        if (kt == (NK) - 1) asm volatile("s_waitcnt vmcnt(0)" ::: "memory");          \
        else                asm volatile("s_waitcnt vmcnt(8)" ::: "memory");          \
        __builtin_amdgcn_s_barrier();                                                 \
        /* ---- ph1: kk1 ---- */                                                      \
        Ar = sA + (p * 2 + 1) * REG; Br = sB + (p * 2 + 1) * REG;                     \
        _Pragma("unroll") for (int m = 0; m < 4; ++m) a[m] = *(const bf16x8*)(Ar + aoff[m]); \
        _Pragma("unroll") for (int n = 0; n < 4; ++n) b[n] = *(const bf16x8*)(Br + boff[n]); \
        if (kt + 2 < (NK)) { STA(p, kt + 2, 0); STB(p, kt + 2, 0); }                  \
        __builtin_amdgcn_s_setprio(1);                                                \
        _Pragma("unroll") for (int m = 0; m < 4; ++m)                                 \
            _Pragma("unroll") for (int n = 0; n < 4; ++n)                             \
                acc[m][n] = __builtin_amdgcn_mfma_f32_16x16x32_bf16(a[m], b[n], acc[m][n], 0, 0, 0); \
        __builtin_amdgcn_s_setprio(0);                                                \
        if (kt < (NK) - 1) {                                                          \
            if (kt < (NK) - 2) asm volatile("s_waitcnt vmcnt(8)" ::: "memory");       \
            else               asm volatile("s_waitcnt vmcnt(4)" ::: "memory");       \
            __builtin_amdgcn_s_barrier();                                             \
        }                                                                             \
    }

// ============ GEMM1: H = gelu(Xg @ w1^T + b1) [128x128, XCD A-share remap] ============
__global__ __launch_bounds__(256, 2) void k_gemm1(const u16* __restrict__ xb,
                                                  const u16* __restrict__ w1b,
                                                  const float* __restrict__ b1,
                                                  const int* __restrict__ tok_idx,
                                                  const Ctrl* __restrict__ ctrl,
                                                  u16* __restrict__ H) {
    int flat = blockIdx.x;
    int t = (flat & 7) + ((flat >> 8) << 3);
    int n0 = ((flat >> 3) & 31) * TILE;
    if (t >= ctrl->n_tiles) return;
    int e = ctrl->tile_expert[t];
    int rbase = ctrl->tile_base[t];

    __shared__ __align__(16) u16 sA[2 * 2 * REG];
    __shared__ __align__(16) u16 sB[2 * 2 * REG];

    int tid = threadIdx.x;
    const u16* aS[2];
    const u16* bS[2];
    int fo[2];
#pragma unroll
    for (int q = 0; q < 2; ++q) {
        int f = q * 256 + tid;                 // 0..511
        int row = f >> 2;                      // 0..127
        int lc = (f & 3) ^ ((row >> 1) & 3);   // inverse-swizzled source chunk
        aS[q] = xb + (size_t)tok_idx[rbase + row] * DMODEL + lc * 8;
        bS[q] = w1b + (size_t)e * DFF * DMODEL + (size_t)(n0 + row) * DMODEL + lc * 8;
        fo[q] = f * 8;
    }

#define STA1(pp, kt, h)                                                               \
    do { _Pragma("unroll") for (int q = 0; q < 2; ++q)                                \
        load16(aS[q] + (kt) * 64 + (h) * 32, &sA[((pp) * 2 + (h)) * REG + fo[q]]); } while (0)
#define STB1(pp, kt, h)                                                               \
    do { _Pragma("unroll") for (int q = 0; q < 2; ++q)                                \
        load16(bS[q] + (kt) * 64 + (h) * 32, &sB[((pp) * 2 + (h)) * REG + fo[q]]); } while (0)

    int lane = tid & 63, w = tid >> 6;
    int wr = w >> 1, wc = w & 1;               // 2M x 2N waves; wave tile 64x64
    int l15 = lane & 15, lg = lane >> 4;
    int csw = (lg ^ ((l15 >> 1) & 3)) * 8;

    int aoff[4], boff[4];
#pragma unroll
    for (int m = 0; m < 4; ++m) aoff[m] = (wr * 64 + m * 16 + l15) * 32 + csw;
#pragma unroll
    for (int n = 0; n < 4; ++n) boff[n] = (wc * 64 + n * 16 + l15) * 32 + csw;

    f32x4 acc[4][4];
#pragma unroll
    for (int m = 0; m < 4; ++m)
#pragma unroll
        for (int n = 0; n < 4; ++n) acc[m][n] = (f32x4){0.f, 0.f, 0.f, 0.f};

    KLOOP2(STA1, STB1, DMODEL / 64)
#undef STA1
#undef STB1

    float bias[4];
#pragma unroll
    for (int n = 0; n < 4; ++n) bias[n] = b1[e * DFF + n0 + wc * 64 + n * 16 + l15];
#pragma unroll
    for (int m = 0; m < 4; ++m)
#pragma unroll
        for (int n = 0; n < 4; ++n) {
            int gcol = n0 + wc * 64 + n * 16 + l15;
#pragma unroll
            for (int r = 0; r < 4; ++r) {
                int grow = wr * 64 + m * 16 + lg * 4 + r;
                float h = acc[m][n][r] + bias[n];
                H[(size_t)(rbase + grow) * DFF + gcol] = f2bf(gelu_fast(h));
            }
        }
}

// ============ GEMM2: y += w * (H @ w2^T + b2) [128x128, XCD A-share remap] ============
__global__ __launch_bounds__(256, 2) void k_gemm2(const u16* __restrict__ H,
                                                  const u16* __restrict__ w2b,
                                                  const float* __restrict__ b2,
                                                  const int* __restrict__ tok_idx,
                                                  const float* __restrict__ tok_w,
                                                  const Ctrl* __restrict__ ctrl,
                                                  float* __restrict__ y) {
    int flat = blockIdx.x;
    int t = (flat & 7) + ((flat >> 6) << 3);
    int n0 = ((flat >> 3) & 7) * TILE;
    if (t >= ctrl->n_tiles) return;
    int e = ctrl->tile_expert[t];
    int rbase = ctrl->tile_base[t];
    int valid = ctrl->tile_valid[t];

    __shared__ __align__(16) u16 sA[2 * 2 * REG];
    __shared__ __align__(16) u16 sB[2 * 2 * REG];

    int tid = threadIdx.x;
    const u16* aS[2];
    const u16* bS[2];
    int fo[2];
#pragma unroll
    for (int q = 0; q < 2; ++q) {
        int f = q * 256 + tid;
        int row = f >> 2;
        int lc = (f & 3) ^ ((row >> 1) & 3);
        aS[q] = H + (size_t)(rbase + row) * DFF + lc * 8;
        bS[q] = w2b + (size_t)e * DMODEL * DFF + (size_t)(n0 + row) * DFF + lc * 8;
        fo[q] = f * 8;
    }

#define STA2(pp, kt, h)                                                               \
    do { _Pragma("unroll") for (int q = 0; q < 2; ++q)                                \
        load16(aS[q] + (kt) * 64 + (h) * 32, &sA[((pp) * 2 + (h)) * REG + fo[q]]); } while (0)
#define STB2(pp, kt, h)                                                               \
    do { _Pragma("unroll") for (int q = 0; q < 2; ++q)                                \
        load16(bS[q] + (kt) * 64 + (h) * 32, &sB[((pp) * 2 + (h)) * REG + fo[q]]); } while (0)

    int lane = tid & 63, w = tid >> 6;
    int wr = w >> 1, wc = w & 1;
    int l15 = lane & 15, lg = lane >> 4;
    int csw = (lg ^ ((l15 >> 1) & 3)) * 8;

    int aoff[4], boff[4];
#pragma unroll
    for (int m = 0; m < 4; ++m) aoff[m] = (wr * 64 + m * 16 + l15) * 32 + csw;
#pragma unroll
    for (int n = 0; n < 4; ++n) boff[n] = (wc * 64 + n * 16 + l15) * 32 + csw;

    f32x4 acc[4][4];
#pragma unroll
    for (int m = 0; m < 4; ++m)
#pragma unroll
        for (int n = 0; n < 4; ++n) acc[m][n] = (f32x4){0.f, 0.f, 0.f, 0.f};

    KLOOP2(STA2, STB2, DFF / 64)
#undef STA2
#undef STB2

    float bias[4];
#pragma unroll
    for (int n = 0; n < 4; ++n) bias[n] = b2[e * DMODEL + n0 + wc * 64 + n * 16 + l15];
#pragma unroll
    for (int m = 0; m < 4; ++m)
#pragma unroll
        for (int n = 0; n < 4; ++n) {
            int gcol = n0 + wc * 64 + n * 16 + l15;
#pragma unroll
            for (int r = 0; r < 4; ++r) {
                int grow = wr * 64 + m * 16 + lg * 4 + r;
                if (grow < valid) {
                    int slot = rbase + grow;
                    int tok = tok_idx[slot];
                    float wgt = tok_w[slot];
                    unsafeAtomicAdd(&y[(size_t)tok * DMODEL + gcol],
                                    wgt * (acc[m][n][r] + bias[n]));
                }
            }
        }
}

// ---------------- finalize ----------------
__global__ void k_final(const Ctrl* __restrict__ ctrl, float* __restrict__ out) {
    if (blockIdx.x == 0 && threadIdx.x == 0) {
        float imp[NEXP], ld[NEXP];
        float imps = 0.f, loads = 0.f;
        for (int e = 0; e < NEXP; ++e) {
            imp[e] = ctrl->imp[e];
            ld[e] = (float)ctrl->counts[e];
            imps += imp[e];
            loads += ld[e];
        }
        float bal = 0.f;
        for (int e = 0; e < NEXP; ++e)
            bal += (imp[e] / (imps + MOE_EPS)) * (ld[e] / (loads + MOE_EPS));
        bal *= (float)NEXP;
        float z = ctrl->zacc / (float)NTOK;
        float aux = 0.01f * bal + 0.001f * z;
        size_t base = (size_t)NTOK * DMODEL;
        out[base] = aux;
        for (int e = 0; e < NEXP; ++e) out[base + 1 + e] = ld[e];
        for (int e = 0; e < NEXP; ++e) out[base + 9 + e] = imp[e];
    }
}

extern "C" void kernel_launch(void* const* d_in, const int* in_sizes, int n_in,
                              void* d_out, int out_size, void* d_ws, size_t ws_size,
                              hipStream_t stream) {
    (void)in_sizes; (void)n_in; (void)out_size; (void)ws_size;
    const float* x  = (const float*)d_in[0];
    const float* rw = (const float*)d_in[1];
    const float* w1 = (const float*)d_in[2];
    const float* b1 = (const float*)d_in[3];
    const float* w2 = (const float*)d_in[4];
    const float* b2 = (const float*)d_in[5];
    float* out = (float*)d_out;

    char* p = (char*)d_ws;
    Ctrl* ctrl = (Ctrl*)p;          p += 4096;
    u16* xb    = (u16*)p;           p += (size_t)NTOK * DMODEL * 2;
    u16* w1b   = (u16*)p;           p += (size_t)NEXP * DFF * DMODEL * 2;
    u16* w2b   = (u16*)p;           p += (size_t)NEXP * DMODEL * DFF * 2;
    u16* Hbuf  = (u16*)p;           p += (size_t)MAXROWS * DFF * 2;
    int* tok_idx = (int*)p;         p += (size_t)MAXROWS * 4;
    float* tok_w = (float*)p;       p += (size_t)MAXROWS * 4;
    int* tIdx  = (int*)p;           p += (size_t)NTOK * 2 * 4;
    float* tW  = (float*)p;         p += (size_t)NTOK * 2 * 4;

    hipMemsetAsync(ctrl, 0, sizeof(Ctrl), stream);
    hipMemsetAsync(d_out, 0, (size_t)NTOK * DMODEL * sizeof(float), stream);

    k_convert<<<2048, 256, 0, stream>>>(w1, w1b, NEXP * DFF * DMODEL / 4);
    k_convert<<<2048, 256, 0, stream>>>(w2, w2b, NEXP * DMODEL * DFF / 4);

    k_router<<<NTOK / 4, 256, 0, stream>>>(x, rw, xb, tIdx, tW, ctrl);
    k_build<<<1, 256, 0, stream>>>(tIdx, ctrl, tok_idx, tok_w);
    k_fill<<<NTOK / 256, 256, 0, stream>>>(tIdx, tW, ctrl, tok_idx, tok_w);

    // 1-D grids; (t, n0) derived in-kernel with XCD-chunked remap
    k_gemm1<<<MAXTILES * (DFF / TILE), 256, 0, stream>>>(xb, w1b, b1, tok_idx, ctrl, Hbuf);
    k_gemm2<<<MAXTILES * (DMODEL / TILE), 256, 0, stream>>>(Hbuf, w2b, b2, tok_idx, tok_w, ctrl, out);

    k_final<<<1, 64, 0, stream>>>(ctrl, out);
}

// Round 12
// 750.514 us; speedup vs baseline: 1.1651x; 1.0746x over previous
//
#include <hip/hip_runtime.h>
#include <math.h>

#define NTOK 8192
#define DMODEL 1024
#define DFF 4096
#define NEXP 8
#define TILE 128
#define MAXTILES 136
#define MAXROWS (MAXTILES * TILE)
#define MOE_EPS 1e-9f
#define REG 4096  // u16 per dbuf region: 128 rows * 32 cols = 8 KB

typedef unsigned short u16;
typedef __bf16 bf16x8 __attribute__((ext_vector_type(8)));
typedef float f32x4 __attribute__((ext_vector_type(4)));

struct Ctrl {
    int counts[NEXP];
    int fill[NEXP];
    int padded_off[NEXP];
    int n_tiles;
    int tile_expert[MAXTILES];
    int tile_base[MAXTILES];
    int tile_valid[MAXTILES];
    float imp[NEXP];
    float zacc;
};

__device__ __forceinline__ u16 f2bf(float f) {
    unsigned u = __float_as_uint(f);
    unsigned r = u + 0x7fffu + ((u >> 16) & 1u);
    return (u16)(r >> 16);
}

__device__ __forceinline__ void load16(const void* g, void* l) {
    __builtin_amdgcn_global_load_lds((__attribute__((address_space(1))) void*)g,
                                     (__attribute__((address_space(3))) void*)l,
                                     16, 0, 0);
}

// fast GELU: h*sigmoid(1.59577h+0.071355h^3) (tanh-form), |err| < 1e-3
__device__ __forceinline__ float gelu_fast(float h) {
    float u = h * (1.5957691216f + 0.0713548162f * h * h);
    return h / (1.f + __expf(-u));
}

// ---------------- fp32 -> bf16 convert (w1, w2) ----------------
__global__ __launch_bounds__(256) void k_convert(const float* __restrict__ src,
                                                 u16* __restrict__ dst, int n4) {
    int i = blockIdx.x * 256 + threadIdx.x;
    int stride = gridDim.x * 256;
    for (; i < n4; i += stride) {
        float4 v = ((const float4*)src)[i];
        ushort4 o;
        o.x = f2bf(v.x); o.y = f2bf(v.y); o.z = f2bf(v.z); o.w = f2bf(v.w);
        ((ushort4*)dst)[i] = o;
    }
}

// ---------------- router (+ fused x->bf16 conversion) ----------------
__global__ __launch_bounds__(256) void k_router(const float* __restrict__ x,
                                                const float* __restrict__ rw,
                                                u16* __restrict__ xb,
                                                int* __restrict__ top_idx,
                                                float* __restrict__ top_w,
                                                Ctrl* __restrict__ ctrl) {
    __shared__ float srw[NEXP * DMODEL];
    __shared__ float simp[NEXP];
    __shared__ float szl;
    int tid = threadIdx.x;
    for (int i = tid; i < NEXP * DMODEL / 4; i += 256)
        ((float4*)srw)[i] = ((const float4*)rw)[i];
    if (tid < NEXP) simp[tid] = 0.f;
    if (tid == 0) szl = 0.f;
    __syncthreads();

    int lane = tid & 63;
    int n = blockIdx.x * 4 + (tid >> 6);
    float p[NEXP];
#pragma unroll
    for (int e = 0; e < NEXP; ++e) p[e] = 0.f;
    const float4* xr = (const float4*)(x + (size_t)n * DMODEL);
    u16 xs[16];
#pragma unroll
    for (int j = 0; j < 4; ++j) {
        float4 xv = xr[lane * 4 + j];
        int d = (lane * 4 + j) * 4;
        xs[j * 4 + 0] = f2bf(xv.x);
        xs[j * 4 + 1] = f2bf(xv.y);
        xs[j * 4 + 2] = f2bf(xv.z);
        xs[j * 4 + 3] = f2bf(xv.w);
#pragma unroll
        for (int e = 0; e < NEXP; ++e) {
            const float* r = srw + e * DMODEL + d;
            p[e] += xv.x * r[0] + xv.y * r[1] + xv.z * r[2] + xv.w * r[3];
        }
    }
    {
        uint4* dst = (uint4*)(xb + (size_t)n * DMODEL + lane * 16);
        dst[0] = ((const uint4*)xs)[0];
        dst[1] = ((const uint4*)xs)[1];
    }
#pragma unroll
    for (int e = 0; e < NEXP; ++e) {
#pragma unroll
        for (int off = 32; off > 0; off >>= 1) p[e] += __shfl_xor(p[e], off);
    }
    if (lane == 0) {
        float m = p[0];
#pragma unroll
        for (int e = 1; e < NEXP; ++e) m = fmaxf(m, p[e]);
        float pr[NEXP];
        float s = 0.f;
#pragma unroll
        for (int e = 0; e < NEXP; ++e) { pr[e] = expf(p[e] - m); s += pr[e]; }
        float inv = 1.f / s;
#pragma unroll
        for (int e = 0; e < NEXP; ++e) pr[e] *= inv;
        float lse = m + logf(s);
        int i0 = 0; float v0 = pr[0];
#pragma unroll
        for (int e = 1; e < NEXP; ++e) if (pr[e] > v0) { v0 = pr[e]; i0 = e; }
        int i1 = -1; float v1 = -1.f;
#pragma unroll
        for (int e = 0; e < NEXP; ++e) if (e != i0 && pr[e] > v1) { v1 = pr[e]; i1 = e; }
        float den = v0 + v1 + MOE_EPS;
        top_idx[n * 2] = i0;
        top_idx[n * 2 + 1] = i1;
        top_w[n * 2] = v0 / den;
        top_w[n * 2 + 1] = v1 / den;
#pragma unroll
        for (int e = 0; e < NEXP; ++e) atomicAdd(&simp[e], pr[e]);
        atomicAdd(&szl, lse * lse);
    }
    __syncthreads();
    if (tid < NEXP) atomicAdd(&ctrl->imp[tid], simp[tid]);
    if (tid == 255) atomicAdd(&ctrl->zacc, szl);
}

// ---------------- build schedule (128-row tiles) ----------------
__global__ __launch_bounds__(256) void k_build(const int* __restrict__ top_idx,
                                               Ctrl* __restrict__ ctrl,
                                               int* __restrict__ tok_idx,
                                               float* __restrict__ tok_w) {
    __shared__ int cnt[NEXP];
    __shared__ int off[NEXP];
    __shared__ int tiles[NEXP];
    int tid = threadIdx.x;
    if (tid < NEXP) cnt[tid] = 0;
    __syncthreads();
    for (int i = tid; i < NTOK * 2; i += 256) atomicAdd(&cnt[top_idx[i]], 1);
    __syncthreads();
    if (tid == 0) {
        int o = 0, t = 0;
        for (int e = 0; e < NEXP; ++e) {
            int c = cnt[e];
            int te = (c + TILE - 1) / TILE;
            ctrl->counts[e] = c;
            ctrl->padded_off[e] = o;
            off[e] = o;
            tiles[e] = te;
            for (int i = 0; i < te; ++i) {
                ctrl->tile_expert[t] = e;
                ctrl->tile_base[t] = o + i * TILE;
                int v = c - i * TILE;
                ctrl->tile_valid[t] = v > TILE ? TILE : v;
                ++t;
            }
            o += te * TILE;
        }
        ctrl->n_tiles = t;
    }
    __syncthreads();
    for (int e = 0; e < NEXP; ++e) {
        int start = off[e] + cnt[e];
        int end = off[e] + tiles[e] * TILE;
        for (int i = start + tid; i < end; i += 256) {
            tok_idx[i] = 0;
            tok_w[i] = 0.f;
        }
    }
}

// ---------------- fill token lists ----------------
__global__ __launch_bounds__(256) void k_fill(const int* __restrict__ top_idx,
                                              const float* __restrict__ top_w,
                                              Ctrl* __restrict__ ctrl,
                                              int* __restrict__ tok_idx,
                                              float* __restrict__ tok_w) {
    int n = blockIdx.x * 256 + threadIdx.x;
    if (n >= NTOK) return;
#pragma unroll
    for (int k = 0; k < 2; ++k) {
        int e = top_idx[n * 2 + k];
        int pos = atomicAdd(&ctrl->fill[e], 1);
        int slot = ctrl->padded_off[e] + pos;
        tok_idx[slot] = n;
        tok_w[slot] = top_w[n * 2 + k];
    }
}

// ======== 128x128, BK=32, dbuf, counted vmcnt(4), 32 KB LDS -> 4 blocks/CU ========
// Per K-tile: vmcnt(4) -> barrier -> 8 ds_read_b128 + 16 MFMA (compiler
// interleaves lgkm waits; MFMA consumption guarantees reads complete before
// the next barrier) -> barrier -> stage kt+2 into the just-freed buffer.
// Ledger: prologue 8 outstanding (kt0,kt1); steady wait vmcnt(4) drains kt's 4,
// stage adds 4; kt=NK-2 no stage -> kt=NK-1 waits vmcnt(0).
// Barrier dead time is covered by 3 sibling blocks on the CU (m114 overlap).
#define KLOOP3(STA, STB, NK)                                                          \
    STA(0, 0); STB(0, 0);                                                             \
    STA(1, 1); STB(1, 1);                                                             \
    for (int kt = 0; kt < (NK); ++kt) {                                               \
        int p = kt & 1;                                                               \
        if (kt < (NK) - 1) asm volatile("s_waitcnt vmcnt(4)" ::: "memory");           \
        else               asm volatile("s_waitcnt vmcnt(0)" ::: "memory");           \
        __builtin_amdgcn_s_barrier();                                                 \
        const u16* Ar = sA + p * REG;                                                 \
        const u16* Br = sB + p * REG;                                                 \
        bf16x8 a[4], b[4];                                                            \
        _Pragma("unroll") for (int m = 0; m < 4; ++m) a[m] = *(const bf16x8*)(Ar + aoff[m]); \
        _Pragma("unroll") for (int n = 0; n < 4; ++n) b[n] = *(const bf16x8*)(Br + boff[n]); \
        __builtin_amdgcn_s_setprio(1);                                                \
        _Pragma("unroll") for (int m = 0; m < 4; ++m)                                 \
            _Pragma("unroll") for (int n = 0; n < 4; ++n)                             \
                acc[m][n] = __builtin_amdgcn_mfma_f32_16x16x32_bf16(a[m], b[n], acc[m][n], 0, 0, 0); \
        __builtin_amdgcn_s_setprio(0);                                                \
        __builtin_amdgcn_s_barrier();                                                 \
        if (kt + 2 < (NK)) { STA(p, kt + 2); STB(p, kt + 2); }                        \
    }

// ============ GEMM1: H = gelu(Xg @ w1^T + b1) [128x128, 4 blocks/CU] ============
__global__ __launch_bounds__(256, 4) void k_gemm1(const u16* __restrict__ xb,
                                                  const u16* __restrict__ w1b,
                                                  const float* __restrict__ b1,
                                                  const int* __restrict__ tok_idx,
                                                  const Ctrl* __restrict__ ctrl,
                                                  u16* __restrict__ H) {
    int flat = blockIdx.x;
    int t = (flat & 7) + ((flat >> 8) << 3);
    int n0 = ((flat >> 3) & 31) * TILE;
    if (t >= ctrl->n_tiles) return;
    int e = ctrl->tile_expert[t];
    int rbase = ctrl->tile_base[t];

    __shared__ __align__(16) u16 sA[2 * REG];
    __shared__ __align__(16) u16 sB[2 * REG];

    int tid = threadIdx.x;
    const u16* aS[2];
    const u16* bS[2];
    int fo[2];
#pragma unroll
    for (int q = 0; q < 2; ++q) {
        int f = q * 256 + tid;                 // 0..511
        int row = f >> 2;                      // 0..127
        int lc = (f & 3) ^ ((row >> 1) & 3);   // inverse-swizzled source chunk
        aS[q] = xb + (size_t)tok_idx[rbase + row] * DMODEL + lc * 8;
        bS[q] = w1b + (size_t)e * DFF * DMODEL + (size_t)(n0 + row) * DMODEL + lc * 8;
        fo[q] = f * 8;
    }

#define STA1(pp, kt)                                                                  \
    do { _Pragma("unroll") for (int q = 0; q < 2; ++q)                                \
        load16(aS[q] + (kt) * 32, &sA[(pp) * REG + fo[q]]); } while (0)
#define STB1(pp, kt)                                                                  \
    do { _Pragma("unroll") for (int q = 0; q < 2; ++q)                                \
        load16(bS[q] + (kt) * 32, &sB[(pp) * REG + fo[q]]); } while (0)

    int lane = tid & 63, w = tid >> 6;
    int wr = w >> 1, wc = w & 1;               // 2M x 2N waves; wave tile 64x64
    int l15 = lane & 15, lg = lane >> 4;
    int csw = (lg ^ ((l15 >> 1) & 3)) * 8;

    int aoff[4], boff[4];
#pragma unroll
    for (int m = 0; m < 4; ++m) aoff[m] = (wr * 64 + m * 16 + l15) * 32 + csw;
#pragma unroll
    for (int n = 0; n < 4; ++n) boff[n] = (wc * 64 + n * 16 + l15) * 32 + csw;

    f32x4 acc[4][4];
#pragma unroll
    for (int m = 0; m < 4; ++m)
#pragma unroll
        for (int n = 0; n < 4; ++n) acc[m][n] = (f32x4){0.f, 0.f, 0.f, 0.f};

    KLOOP3(STA1, STB1, DMODEL / 32)
#undef STA1
#undef STB1

    float bias[4];
#pragma unroll
    for (int n = 0; n < 4; ++n) bias[n] = b1[e * DFF + n0 + wc * 64 + n * 16 + l15];
#pragma unroll
    for (int m = 0; m < 4; ++m)
#pragma unroll
        for (int n = 0; n < 4; ++n) {
            int gcol = n0 + wc * 64 + n * 16 + l15;
#pragma unroll
            for (int r = 0; r < 4; ++r) {
                int grow = wr * 64 + m * 16 + lg * 4 + r;
                float h = acc[m][n][r] + bias[n];
                H[(size_t)(rbase + grow) * DFF + gcol] = f2bf(gelu_fast(h));
            }
        }
}

// ============ GEMM2: y += w * (H @ w2^T + b2) [128x128, 4 blocks/CU] ============
__global__ __launch_bounds__(256, 4) void k_gemm2(const u16* __restrict__ H,
                                                  const u16* __restrict__ w2b,
                                                  const float* __restrict__ b2,
                                                  const int* __restrict__ tok_idx,
                                                  const float* __restrict__ tok_w,
                                                  const Ctrl* __restrict__ ctrl,
                                                  float* __restrict__ y) {
    int flat = blockIdx.x;
    int t = (flat & 7) + ((flat >> 6) << 3);
    int n0 = ((flat >> 3) & 7) * TILE;
    if (t >= ctrl->n_tiles) return;
    int e = ctrl->tile_expert[t];
    int rbase = ctrl->tile_base[t];
    int valid = ctrl->tile_valid[t];

    __shared__ __align__(16) u16 sA[2 * REG];
    __shared__ __align__(16) u16 sB[2 * REG];

    int tid = threadIdx.x;
    const u16* aS[2];
    const u16* bS[2];
    int fo[2];
#pragma unroll
    for (int q = 0; q < 2; ++q) {
        int f = q * 256 + tid;
        int row = f >> 2;
        int lc = (f & 3) ^ ((row >> 1) & 3);
        aS[q] = H + (size_t)(rbase + row) * DFF + lc * 8;
        bS[q] = w2b + (size_t)e * DMODEL * DFF + (size_t)(n0 + row) * DFF + lc * 8;
        fo[q] = f * 8;
    }

#define STA2(pp, kt)                                                                  \
    do { _Pragma("unroll") for (int q = 0; q < 2; ++q)                                \
        load16(aS[q] + (kt) * 32, &sA[(pp) * REG + fo[q]]); } while (0)
#define STB2(pp, kt)                                                                  \
    do { _Pragma("unroll") for (int q = 0; q < 2; ++q)                                \
        load16(bS[q] + (kt) * 32, &sB[(pp) * REG + fo[q]]); } while (0)

    int lane = tid & 63, w = tid >> 6;
    int wr = w >> 1, wc = w & 1;
    int l15 = lane & 15, lg = lane >> 4;
    int csw = (lg ^ ((l15 >> 1) & 3)) * 8;

    int aoff[4], boff[4];
#pragma unroll
    for (int m = 0; m < 4; ++m) aoff[m] = (wr * 64 + m * 16 + l15) * 32 + csw;
#pragma unroll
    for (int n = 0; n < 4; ++n) boff[n] = (wc * 64 + n * 16 + l15) * 32 + csw;

    f32x4 acc[4][4];
#pragma unroll
    for (int m = 0; m < 4; ++m)
#pragma unroll
        for (int n = 0; n < 4; ++n) acc[m][n] = (f32x4){0.f, 0.f, 0.f, 0.f};

    KLOOP3(STA2, STB2, DFF / 32)
#undef STA2
#undef STB2

    float bias[4];
#pragma unroll
    for (int n = 0; n < 4; ++n) bias[n] = b2[e * DMODEL + n0 + wc * 64 + n * 16 + l15];
#pragma unroll
    for (int m = 0; m < 4; ++m)
#pragma unroll
        for (int n = 0; n < 4; ++n) {
            int gcol = n0 + wc * 64 + n * 16 + l15;
#pragma unroll
            for (int r = 0; r < 4; ++r) {
                int grow = wr * 64 + m * 16 + lg * 4 + r;
                if (grow < valid) {
                    int slot = rbase + grow;
                    int tok = tok_idx[slot];
                    float wgt = tok_w[slot];
                    unsafeAtomicAdd(&y[(size_t)tok * DMODEL + gcol],
                                    wgt * (acc[m][n][r] + bias[n]));
                }
            }
        }
}

// ---------------- finalize ----------------
__global__ void k_final(const Ctrl* __restrict__ ctrl, float* __restrict__ out) {
    if (blockIdx.x == 0 && threadIdx.x == 0) {
        float imp[NEXP], ld[NEXP];
        float imps = 0.f, loads = 0.f;
        for (int e = 0; e < NEXP; ++e) {
            imp[e] = ctrl->imp[e];
            ld[e] = (float)ctrl->counts[e];
            imps += imp[e];
            loads += ld[e];
        }
        float bal = 0.f;
        for (int e = 0; e < NEXP; ++e)
            bal += (imp[e] / (imps + MOE_EPS)) * (ld[e] / (loads + MOE_EPS));
        bal *= (float)NEXP;
        float z = ctrl->zacc / (float)NTOK;
        float aux = 0.01f * bal + 0.001f * z;
        size_t base = (size_t)NTOK * DMODEL;
        out[base] = aux;
        for (int e = 0; e < NEXP; ++e) out[base + 1 + e] = ld[e];
        for (int e = 0; e < NEXP; ++e) out[base + 9 + e] = imp[e];
    }
}

extern "C" void kernel_launch(void* const* d_in, const int* in_sizes, int n_in,
                              void* d_out, int out_size, void* d_ws, size_t ws_size,
                              hipStream_t stream) {
    (void)in_sizes; (void)n_in; (void)out_size; (void)ws_size;
    const float* x  = (const float*)d_in[0];
    const float* rw = (const float*)d_in[1];
    const float* w1 = (const float*)d_in[2];
    const float* b1 = (const float*)d_in[3];
    const float* w2 = (const float*)d_in[4];
    const float* b2 = (const float*)d_in[5];
    float* out = (float*)d_out;

    char* p = (char*)d_ws;
    Ctrl* ctrl = (Ctrl*)p;          p += 4096;
    u16* xb    = (u16*)p;           p += (size_t)NTOK * DMODEL * 2;
    u16* w1b   = (u16*)p;           p += (size_t)NEXP * DFF * DMODEL * 2;
    u16* w2b   = (u16*)p;           p += (size_t)NEXP * DMODEL * DFF * 2;
    u16* Hbuf  = (u16*)p;           p += (size_t)MAXROWS * DFF * 2;
    int* tok_idx = (int*)p;         p += (size_t)MAXROWS * 4;
    float* tok_w = (float*)p;       p += (size_t)MAXROWS * 4;
    int* tIdx  = (int*)p;           p += (size_t)NTOK * 2 * 4;
    float* tW  = (float*)p;         p += (size_t)NTOK * 2 * 4;

    hipMemsetAsync(ctrl, 0, sizeof(Ctrl), stream);
    hipMemsetAsync(d_out, 0, (size_t)NTOK * DMODEL * sizeof(float), stream);

    k_convert<<<2048, 256, 0, stream>>>(w1, w1b, NEXP * DFF * DMODEL / 4);
    k_convert<<<2048, 256, 0, stream>>>(w2, w2b, NEXP * DMODEL * DFF / 4);

    k_router<<<NTOK / 4, 256, 0, stream>>>(x, rw, xb, tIdx, tW, ctrl);
    k_build<<<1, 256, 0, stream>>>(tIdx, ctrl, tok_idx, tok_w);
    k_fill<<<NTOK / 256, 256, 0, stream>>>(tIdx, tW, ctrl, tok_idx, tok_w);

    // 1-D grids; (t, n0) derived in-kernel with XCD-chunked remap
    k_gemm1<<<MAXTILES * (DFF / TILE), 256, 0, stream>>>(xb, w1b, b1, tok_idx, ctrl, Hbuf);
    k_gemm2<<<MAXTILES * (DMODEL / TILE), 256, 0, stream>>>(Hbuf, w2b, b2, tok_idx, tok_w, ctrl, out);

    k_final<<<1, 64, 0, stream>>>(ctrl, out);
}